// Round 14
// baseline (191.822 us; speedup 1.0000x reference)
//
#include <hip/hip_runtime.h>
#include <hip/hip_bf16.h>
#include <stdint.h>

typedef float    f32x4  __attribute__((ext_vector_type(4)));
typedef __bf16   bf16x8 __attribute__((ext_vector_type(8)));
typedef __bf16   bf16x2 __attribute__((ext_vector_type(2)));
typedef uint16_t u16;

#define NHEADS 16
#define DKV    64
#define DMODEL 1024
#define BATCH  2
#define SEQ    2048
#define ROWS   4096   /* BATCH*SEQ */

#define EXP2F(x) __builtin_amdgcn_exp2f(x)

__device__ __forceinline__ u16 f2bf(float f) {
  __bf16 h = (__bf16)f;
  union { __bf16 h; u16 u; } c; c.h = h; return c.u;
}
__device__ __forceinline__ uint32_t pk2(float a, float b) {
  union { bf16x2 v; uint32_t u; } c;
  c.v = (bf16x2){(__bf16)a, (__bf16)b};
  return c.u;
}

__device__ __forceinline__ void gload16(const void* g, void* l) {
  __builtin_amdgcn_global_load_lds(
      (const __attribute__((address_space(1))) uint32_t*)g,
      (__attribute__((address_space(3))) uint32_t*)l, 16, 0, 0);
}

__device__ __forceinline__ f32x4 mfma16(bf16x8 a, bf16x8 b, f32x4 c) {
  return __builtin_amdgcn_mfma_f32_16x16x32_bf16(a, b, c, 0, 0, 0);
}

// ------- K1: fused prep. blocks 0..2047: cast x fp32->bf16 (8 elem/thread)
// -------     blocks 2048..2815: wq/wk/wv -> wt[3072][1024] (B^T)
// -------     blocks 2816..3071: wo -> wot[1024][1024] (B^T)
__global__ void prep_kernel(const float* __restrict__ x, u16* __restrict__ xb,
                            const float* __restrict__ wq, const float* __restrict__ wk,
                            const float* __restrict__ wv, const float* __restrict__ wo,
                            u16* __restrict__ wt, u16* __restrict__ wot) {
  int blk = blockIdx.x, tid = threadIdx.x;
  if (blk < 2048) {
    int i = blk * 256 + tid;
    const float4* p = (const float4*)(x + (size_t)i * 8);
    float4 a = p[0], b = p[1];
    uint32_t o0 = pk2(a.x, a.y), o1 = pk2(a.z, a.w);
    uint32_t o2 = pk2(b.x, b.y), o3 = pk2(b.z, b.w);
    uint4 pk = make_uint4(o0, o1, o2, o3);
    *(uint4*)(xb + (size_t)i * 8) = pk;
    return;
  }
  __shared__ float t[64][65];
  int wblk = blk - 2048;
  const float* src; u16* dst; int sld, dld;
  if (wblk < 768) {
    int p = wblk >> 8, rem = wblk & 255;
    int h = rem >> 4, dt = rem & 15;
    const float* w = (p == 0) ? wq : (p == 1) ? wk : wv;
    src = w + ((size_t)h * 1024 + dt * 64) * 64;   sld = 64;   // [64 d][64 dk]
    dst = wt + ((size_t)(p * 1024 + h * 64)) * 1024 + dt * 64; dld = 1024;
  } else {
    int t2 = wblk - 768, rt = t2 >> 4, ct = t2 & 15;
    src = wo + (size_t)(rt * 64) * 1024 + ct * 64;  sld = 1024;
    dst = wot + (size_t)(ct * 64) * 1024 + rt * 64; dld = 1024;
  }
#pragma unroll
  for (int i = 0; i < 16; i++) {
    int e = tid + i * 256, r = e >> 6, c = e & 63;
    t[r][c] = src[(size_t)r * sld + c];
  }
  __syncthreads();
#pragma unroll
  for (int i = 0; i < 16; i++) {
    int e = tid + i * 256, r = e >> 6, c = e & 63;
    dst[(size_t)r * dld + c] = f2bf(t[c][r]);   // dst[r][c] = src[c][r]
  }
}

// ---- K2: fused QKV GEMM, BK=64, dbuf 2-phase (stage-early, 1 barrier/iter),
// ---- XOR-swizzled LDS, 768 blocks of 128x128 ------------------------------
// blocks 0..511:  [Q|K] = xb[4096][1024] * wt(rows 0..2047)^T, scatter epilogue
// blocks 512..767: V^T[1024][4096] = wt(rows 2048..3071) * xb^T, coalesced
__global__ __launch_bounds__(256) void qkv_gemm(
    const u16* __restrict__ xb, const u16* __restrict__ wt,
    u16* __restrict__ qout, u16* __restrict__ kout, u16* __restrict__ vout) {
  __shared__ __align__(16) u16 As[2][128 * 64];   // 2 x 16KB, swizzled rows
  __shared__ __align__(16) u16 Bs[2][128 * 64];   // 2 x 16KB
  int tid = threadIdx.x, l = tid & 63, w = tid >> 6;
  int cpx = gridDim.x >> 3;
  int bid = (blockIdx.x & 7) * cpx + (blockIdx.x >> 3);   // bijective XCD swizzle
  bool vpath = bid >= 512;
  const u16 *A, *Bt; int m0, n0;
  if (!vpath) { A = xb; Bt = wt; m0 = (bid >> 4) * 128; n0 = (bid & 15) * 128; }
  else { int b2 = bid - 512; A = wt + (size_t)2048 * 1024; Bt = xb;
         m0 = (b2 >> 5) * 128; n0 = (b2 & 31) * 128; }
  int wm = (w >> 1) * 64, wn = (w & 1) * 64;
  int cg = l >> 4, cl = l & 15;
  int scb = (l & 7) ^ (l >> 3);                // pre-swizzled 16B chunk idx
  int swz = (cl & 7) << 4;                     // read-side XOR
  int srow = w * 32 + (l >> 3);                // staging row base for this lane

  f32x4 acc[4][4];
#pragma unroll
  for (int i = 0; i < 4; i++)
#pragma unroll
    for (int j = 0; j < 4; j++) acc[i][j] = (f32x4){0.f, 0.f, 0.f, 0.f};

  const u16* ga0 = A  + (size_t)(m0 + srow) * 1024 + scb * 8;
  const u16* gb0 = Bt + (size_t)(n0 + srow) * 1024 + scb * 8;

  // prologue: stage tile 0
#pragma unroll
  for (int j = 0; j < 4; j++) {
    gload16(ga0 + (size_t)(j * 8) * 1024, &As[0][(w * 32 + j * 8) * 64]);
    gload16(gb0 + (size_t)(j * 8) * 1024, &Bs[0][(w * 32 + j * 8) * 64]);
  }
  __syncthreads();

  int cur = 0;
  for (int it = 0; it < 16; ++it) {
    if (it < 15) {    // issue next tile FIRST; latency hides under compute below
      const u16* ga = ga0 + (it + 1) * 64;
      const u16* gb = gb0 + (it + 1) * 64;
#pragma unroll
      for (int j = 0; j < 4; j++) {
        gload16(ga + (size_t)(j * 8) * 1024, &As[cur ^ 1][(w * 32 + j * 8) * 64]);
        gload16(gb + (size_t)(j * 8) * 1024, &Bs[cur ^ 1][(w * 32 + j * 8) * 64]);
      }
    }

    bf16x8 af[4][2], bfr[4][2];
#pragma unroll
    for (int mi = 0; mi < 4; mi++) {
      const char* ap = (const char*)&As[cur][(wm + mi * 16 + cl) * 64];
      af[mi][0] = *(const bf16x8*)(ap + ((cg * 16)      ^ swz));
      af[mi][1] = *(const bf16x8*)(ap + ((64 + cg * 16) ^ swz));
    }
#pragma unroll
    for (int ni = 0; ni < 4; ni++) {
      const char* bp = (const char*)&Bs[cur][(wn + ni * 16 + cl) * 64];
      bfr[ni][0] = *(const bf16x8*)(bp + ((cg * 16)      ^ swz));
      bfr[ni][1] = *(const bf16x8*)(bp + ((64 + cg * 16) ^ swz));
    }
    __builtin_amdgcn_s_setprio(1);
#pragma unroll
    for (int mi = 0; mi < 4; mi++)
#pragma unroll
      for (int ni = 0; ni < 4; ni++) {
        acc[mi][ni] = mfma16(af[mi][0], bfr[ni][0], acc[mi][ni]);
        acc[mi][ni] = mfma16(af[mi][1], bfr[ni][1], acc[mi][ni]);
      }
    __builtin_amdgcn_s_setprio(0);

    __syncthreads();   // drains own lgkm (buf reuse safe) + vmcnt (next tile in)
    cur ^= 1;
  }

  // epilogue: C/D layout col = lane&15, row = (lane>>4)*4 + reg
#pragma unroll
  for (int mi = 0; mi < 4; mi++)
#pragma unroll
    for (int ni = 0; ni < 4; ni++) {
      int nbase = n0 + wn + ni * 16 + cl;
#pragma unroll
      for (int r = 0; r < 4; r++) {
        int m = m0 + wm + mi * 16 + cg * 4 + r;
        float v = acc[mi][ni][r];
        if (!vpath) {
          int p = nbase >> 10, hh = (nbase >> 6) & 15, dk = nbase & 63;
          int b = m >> 11, s = m & 2047;
          size_t o = ((size_t)(b * 16 + hh) * 2048 + s) * 64 + dk;
          // fold 1/sqrt(64)*log2(e) into Q so softmax uses exp2
          if (p == 0) qout[o] = f2bf(v * 0.18033688f);
          else        kout[o] = f2bf(v);
        } else {
          vout[(size_t)m * 4096 + nbase] = f2bf(v);   // V^T [dk_tot][b*2048+s]
        }
      }
    }
}

// ---- K4: out-proj GEMM, BK=64 dbuf 2-phase, 128x64 tiles, 512 blocks ------
__global__ __launch_bounds__(256) void out_gemm(
    const u16* __restrict__ A, const u16* __restrict__ Bt,
    const float* __restrict__ xres, float* __restrict__ fout) {
  __shared__ __align__(16) u16 As[2][128 * 64];   // 2 x 16KB
  __shared__ __align__(16) u16 Bs[2][64 * 64];    // 2 x 8KB
  int tid = threadIdx.x, l = tid & 63, w = tid >> 6;
  int cpx = gridDim.x >> 3;
  int bid = (blockIdx.x & 7) * cpx + (blockIdx.x >> 3);
  int m0 = (bid >> 4) * 128, n0 = (bid & 15) * 64;
  int wm = (w >> 1) * 64, wn = (w & 1) * 32;
  int cg = l >> 4, cl = l & 15;
  int scb = (l & 7) ^ (l >> 3);
  int swz = (cl & 7) << 4;
  int srowA = w * 32 + (l >> 3);
  int srowB = w * 16 + (l >> 3);

  f32x4 acc[4][2];
#pragma unroll
  for (int i = 0; i < 4; i++)
#pragma unroll
    for (int j = 0; j < 2; j++) acc[i][j] = (f32x4){0.f, 0.f, 0.f, 0.f};

  const u16* ga0 = A  + (size_t)(m0 + srowA) * 1024 + scb * 8;
  const u16* gb0 = Bt + (size_t)(n0 + srowB) * 1024 + scb * 8;

  // prologue: stage tile 0
#pragma unroll
  for (int j = 0; j < 4; j++)
    gload16(ga0 + (size_t)(j * 8) * 1024, &As[0][(w * 32 + j * 8) * 64]);
#pragma unroll
  for (int j = 0; j < 2; j++)
    gload16(gb0 + (size_t)(j * 8) * 1024, &Bs[0][(w * 16 + j * 8) * 64]);
  __syncthreads();

  int cur = 0;
  for (int it = 0; it < 16; ++it) {
    if (it < 15) {
      const u16* ga = ga0 + (it + 1) * 64;
      const u16* gb = gb0 + (it + 1) * 64;
#pragma unroll
      for (int j = 0; j < 4; j++)
        gload16(ga + (size_t)(j * 8) * 1024, &As[cur ^ 1][(w * 32 + j * 8) * 64]);
#pragma unroll
      for (int j = 0; j < 2; j++)
        gload16(gb + (size_t)(j * 8) * 1024, &Bs[cur ^ 1][(w * 16 + j * 8) * 64]);
    }

    bf16x8 af[4][2], bfr[2][2];
#pragma unroll
    for (int mi = 0; mi < 4; mi++) {
      const char* ap = (const char*)&As[cur][(wm + mi * 16 + cl) * 64];
      af[mi][0] = *(const bf16x8*)(ap + ((cg * 16)      ^ swz));
      af[mi][1] = *(const bf16x8*)(ap + ((64 + cg * 16) ^ swz));
    }
#pragma unroll
    for (int ni = 0; ni < 2; ni++) {
      const char* bp = (const char*)&Bs[cur][(wn + ni * 16 + cl) * 64];
      bfr[ni][0] = *(const bf16x8*)(bp + ((cg * 16)      ^ swz));
      bfr[ni][1] = *(const bf16x8*)(bp + ((64 + cg * 16) ^ swz));
    }
    __builtin_amdgcn_s_setprio(1);
#pragma unroll
    for (int mi = 0; mi < 4; mi++)
#pragma unroll
      for (int ni = 0; ni < 2; ni++) {
        acc[mi][ni] = mfma16(af[mi][0], bfr[ni][0], acc[mi][ni]);
        acc[mi][ni] = mfma16(af[mi][1], bfr[ni][1], acc[mi][ni]);
      }
    __builtin_amdgcn_s_setprio(0);

    __syncthreads();
    cur ^= 1;
  }

#pragma unroll
  for (int mi = 0; mi < 4; mi++)
#pragma unroll
    for (int ni = 0; ni < 2; ni++) {
      int nbase = n0 + wn + ni * 16 + cl;
#pragma unroll
      for (int r = 0; r < 4; r++) {
        int m = m0 + wm + mi * 16 + cg * 4 + r;
        size_t o = (size_t)m * 1024 + nbase;
        fout[o] = acc[mi][ni][r] + xres[o];
      }
    }
}

// ---- K3: flash attention, quad-buffered K/V, barrier every 2 tiles --------
// 4 waves x 32 q = 128 q/block; grid 512 = 8 XCD x (4 bh x 16 qt), 2 blk/CU.
// Quad-buffer: stage tile t+2 into slot (t+2)&3; __syncthreads only after odd
// t. Fixed-shift softmax (shift 16, log2 domain, via MFMA C-init).
__global__ __launch_bounds__(256) void attn_kernel(
    const u16* __restrict__ q, const u16* __restrict__ k,
    const u16* __restrict__ vt, u16* __restrict__ z) {
  __shared__ __align__(16) u16 Ks[4][64 * 64];   // [kv][d] tiles, 8KB each
  __shared__ __align__(16) u16 Vs[4][64 * 64];   // [d][kv] tiles
  __shared__ __align__(16) u16 Ps[4][32 * 64];   // per-wave P [q32][kv64], 4KB
  int tid = threadIdx.x, l = tid & 63, w = tid >> 6;
  int blk = blockIdx.x;
  int xcd = blk & 7, slot0 = blk >> 3;           // slot 0..63
  int bh = xcd * 4 + (slot0 >> 4), qt = slot0 & 15;
  int b = bh >> 4, h = bh & 15;
  int q0 = qt * 128 + w * 32;
  int cg = l >> 4, cl = l & 15;
  int swz = (cl & 7) << 4;                       // read-side XOR (row&7 == cl&7)

  const u16* qb = q  + ((size_t)bh * 2048 + q0) * 64;
  const u16* kb = k  + (size_t)bh * 2048 * 64;
  const u16* vb = vt + (size_t)(h * 64) * 4096 + b * 2048;

  // staging: wave w fills tile rows w*16..w*16+15 (two 1KB gload16 calls each)
  int srow = w * 16 + (l >> 3);
  int scb  = (l & 7) ^ (l >> 3);                 // pre-swizzled 16B chunk idx

  // Q fragments: qf in {0,1}, col = q = qf*16+cl (Q pre-scaled upstream)
  bf16x8 bq0[2], bq1[2];
#pragma unroll
  for (int qf = 0; qf < 2; qf++) {
    bq0[qf] = *(const bf16x8*)&qb[(size_t)(qf * 16 + cl) * 64 + cg * 8];
    bq1[qf] = *(const bf16x8*)&qb[(size_t)(qf * 16 + cl) * 64 + 32 + cg * 8];
  }

  f32x4 oacc[2][4];   // oacc[qf][nd][r] = Z[d = nd*16+cg*4+r][q = qf*16+cl]
#pragma unroll
  for (int qf = 0; qf < 2; qf++)
#pragma unroll
    for (int i = 0; i < 4; i++) oacc[qf][i] = (f32x4){0.f, 0.f, 0.f, 0.f};
  float lsum[2] = {0.f, 0.f};

  // prologue: stage tiles 0,1
#pragma unroll
  for (int tt = 0; tt < 2; tt++) {
    gload16(kb + ((size_t)tt * 64 + srow) * 64 + scb * 8,       &Ks[tt][(w * 16) * 64]);
    gload16(kb + ((size_t)tt * 64 + srow + 8) * 64 + scb * 8,   &Ks[tt][(w * 16 + 8) * 64]);
    gload16(vb + (size_t)srow * 4096 + tt * 64 + scb * 8,       &Vs[tt][(w * 16) * 64]);
    gload16(vb + (size_t)(srow + 8) * 4096 + tt * 64 + scb * 8, &Vs[tt][(w * 16 + 8) * 64]);
  }
  __syncthreads();

  for (int t = 0; t < 32; t++) {
    int cur = t & 3;
    if (t + 2 < 32) {
      int ns = (t + 2) & 3;
      gload16(kb + ((size_t)(t + 2) * 64 + srow) * 64 + scb * 8,       &Ks[ns][(w * 16) * 64]);
      gload16(kb + ((size_t)(t + 2) * 64 + srow + 8) * 64 + scb * 8,   &Ks[ns][(w * 16 + 8) * 64]);
      gload16(vb + (size_t)srow * 4096 + (t + 2) * 64 + scb * 8,       &Vs[ns][(w * 16) * 64]);
      gload16(vb + (size_t)(srow + 8) * 4096 + (t + 2) * 64 + scb * 8, &Vs[ns][(w * 16 + 8) * 64]);
    }

    // --- QK^T swapped: sc[qf][g][r] = S[kv=g*16+cg*4+r][q=qf*16+cl] - 16
    f32x4 sc[2][4];
    __builtin_amdgcn_s_setprio(1);
#pragma unroll
    for (int g = 0; g < 4; g++) {
      const char* kp = (const char*)&Ks[cur][(g * 16 + cl) * 64];
      bf16x8 a0 = *(const bf16x8*)(kp + ((cg * 16)      ^ swz));
      bf16x8 a1 = *(const bf16x8*)(kp + ((cg * 16 + 64) ^ swz));
#pragma unroll
      for (int qf = 0; qf < 2; qf++) {
        f32x4 t2 = (f32x4){-16.f, -16.f, -16.f, -16.f};
        t2 = mfma16(a0, bq0[qf], t2);
        t2 = mfma16(a1, bq1[qf], t2);
        sc[qf][g] = t2;
      }
    }
    __builtin_amdgcn_s_setprio(0);

    // --- fixed-shift softmax: p = exp2(s - 16), per-lane running sums
#pragma unroll
    for (int qf = 0; qf < 2; qf++) {
      float rs = 0.f;
#pragma unroll
      for (int g = 0; g < 4; g++)
#pragma unroll
        for (int r = 0; r < 4; r++) {
          float p = EXP2F(sc[qf][g][r]);
          sc[qf][g][r] = p;
          rs += p;
        }
      lsum[qf] += rs;
    }

    // --- P -> LDS [q][kv], XOR-swizzled rows, packed 8B writes
    bf16x8 pb0[2], pb1[2];
#pragma unroll
    for (int qf = 0; qf < 2; qf++) {
      char* pw = (char*)&Ps[w][(qf * 16 + cl) * 64];
#pragma unroll
      for (int g = 0; g < 4; g++) {
        uint32_t lo = pk2(sc[qf][g][0], sc[qf][g][1]);
        uint32_t hi = pk2(sc[qf][g][2], sc[qf][g][3]);
        *(uint2*)(pw + ((g * 32 + cg * 8) ^ swz)) = make_uint2(lo, hi);
      }
      pb0[qf] = *(const bf16x8*)(pw + ((cg * 16)      ^ swz));
      pb1[qf] = *(const bf16x8*)(pw + ((cg * 16 + 64) ^ swz));
    }

    // --- PV swapped: oacc[qf][nd] += Vt rows (d) x P[qf]
    __builtin_amdgcn_s_setprio(1);
#pragma unroll
    for (int nd = 0; nd < 4; nd++) {
      const char* vp = (const char*)&Vs[cur][(nd * 16 + cl) * 64];
      bf16x8 v0 = *(const bf16x8*)(vp + ((cg * 16)      ^ swz));
      bf16x8 v1 = *(const bf16x8*)(vp + ((cg * 16 + 64) ^ swz));
#pragma unroll
      for (int qf = 0; qf < 2; qf++) {
        oacc[qf][nd] = mfma16(v0, pb0[qf], oacc[qf][nd]);
        oacc[qf][nd] = mfma16(v1, pb1[qf], oacc[qf][nd]);
      }
    }
    __builtin_amdgcn_s_setprio(0);

    if (t & 1) __syncthreads();   // one drain per TWO tiles (quad-buffer)
  }

  // --- epilogue: per-qf cross-lane reduce, then store
#pragma unroll
  for (int qf = 0; qf < 2; qf++) {
    float ls = lsum[qf];
    ls += __shfl_xor(ls, 16);
    ls += __shfl_xor(ls, 32);
    float inv = 1.0f / ls;
    u16* zb = z + ((size_t)(b * 2048) + q0 + qf * 16 + cl) * 1024 + h * 64;
#pragma unroll
    for (int nd = 0; nd < 4; nd++) {
      uint32_t lo = pk2(oacc[qf][nd][0] * inv, oacc[qf][nd][1] * inv);
      uint32_t hi = pk2(oacc[qf][nd][2] * inv, oacc[qf][nd][3] * inv);
      *(uint2*)&zb[nd * 16 + cg * 4] = make_uint2(lo, hi);
    }
  }
}

// --------------------------------------------------------------------------
extern "C" void kernel_launch(void* const* d_in, const int* in_sizes, int n_in,
                              void* d_out, int out_size, void* d_ws, size_t ws_size,
                              hipStream_t stream) {
  const float* x  = (const float*)d_in[0];
  const float* wq = (const float*)d_in[1];
  const float* wk = (const float*)d_in[2];
  const float* wv = (const float*)d_in[3];
  const float* wo = (const float*)d_in[4];
  float* out = (float*)d_out;

  uint8_t* ws = (uint8_t*)d_ws;
  u16* xb  = (u16*)(ws);                       // 8 MiB  [4096][1024]
  u16* wt  = (u16*)(ws + (8ull  << 20));       // 6 MiB  [3072][1024]
  u16* wot = (u16*)(ws + (14ull << 20));       // 2 MiB  [1024][1024]
  u16* qb  = (u16*)(ws + (16ull << 20));       // 8 MiB  [B,H,S,64]
  u16* kb  = (u16*)(ws + (24ull << 20));       // 8 MiB
  u16* vt  = (u16*)(ws + (32ull << 20));       // 8 MiB  [1024][4096] = V^T
  u16* zb  = (u16*)(ws + (40ull << 20));       // 8 MiB  [4096][1024]
  if (ws_size < (48ull << 20)) return;         // need 48 MiB scratch

  prep_kernel<<<3072, 256, 0, stream>>>(x, xb, wq, wk, wv, wo, wt, wot);
  qkv_gemm<<<768, 256, 0, stream>>>(xb, wt, qb, kb, vt);
  attn_kernel<<<512, 256, 0, stream>>>(qb, kb, vt, zb);
  out_gemm<<<512, 256, 0, stream>>>(zb, wot, x, out);
}